// Round 6
// baseline (269.447 us; speedup 1.0000x reference)
//
#include <hip/hip_runtime.h>
#include <hip/hip_bf16.h>
#include <stdint.h>

#define AS1 __attribute__((address_space(1)))
#define AS3 __attribute__((address_space(3)))

typedef __bf16 bf16x8 __attribute__((ext_vector_type(8)));
typedef float  f32x4  __attribute__((ext_vector_type(4)));
typedef unsigned short ushort8v __attribute__((ext_vector_type(8)));
typedef unsigned short ushort4v __attribute__((ext_vector_type(4)));
typedef short short8v __attribute__((ext_vector_type(8)));
typedef short short4v __attribute__((ext_vector_type(4)));

__device__ __forceinline__ unsigned short f2bf(float f) {
    unsigned int u = __float_as_uint(f);
    u += 0x7fffu + ((u >> 16) & 1u);           // round-to-nearest-even
    return (unsigned short)(u >> 16);
}
__device__ __forceinline__ unsigned int pk2bf(float a, float b) {
    __hip_bfloat162 h = __float22bfloat162_rn(make_float2(a, b));  // x->low short
    unsigned int u;
    __builtin_memcpy(&u, &h, 4);
    return u;
}
__device__ __forceinline__ void g2lds16(const void* gp, void* lp) {
    __builtin_amdgcn_global_load_lds((AS1 void*)gp, (AS3 void*)lp, 16, 0, 0);
}
#define E2(x) __builtin_amdgcn_exp2f(x)

// ---------------- cast fp32 -> bf16 ----------------
__global__ __launch_bounds__(256) void cast_x_k(const float* __restrict__ src,
                                                unsigned short* __restrict__ dst) {
    int i = (blockIdx.x * 256 + threadIdx.x) * 4;
    float4 v = *(const float4*)(src + i);
    ushort4v o = { f2bf(v.x), f2bf(v.y), f2bf(v.z), f2bf(v.w) };
    *(ushort4v*)(dst + i) = o;
}

__global__ __launch_bounds__(256) void cast_w_k(const float* __restrict__ w0,
                                                const float* __restrict__ w1,
                                                const float* __restrict__ w2,
                                                unsigned short* __restrict__ dst) {
    int z = blockIdx.z;
    const float* s = (z == 0) ? w0 : (z == 1) ? w1 : w2;
    int i = (blockIdx.x * 256 + threadIdx.x) * 4;
    float4 v = *(const float4*)(s + i);
    ushort4v o = { f2bf(v.x), f2bf(v.y), f2bf(v.z), f2bf(v.w) };
    *(ushort4v*)(dst + (size_t)z * 1048576 + i) = o;
}

// ---------------- QKV GEMM: out = X @ W^T (NT), BK=64, XOR-swizzled LDS -----
// g2lds16 forces LDS rows contiguous (128B at BK=64 -> 16-way read conflicts),
// so each lane stages global 16B-chunk ((l&7)^(l>>3)) instead of (l&7); LDS
// holds chunk cb at slot cb^(row&7). Readers XOR with cl&7 -> 2-way (free).
// Halves barrier count and staging-instruction count vs BK=32.
// Q (z=0) pre-scaled by 0.125*log2(e) so attn can exp2 scores directly.
__global__ __launch_bounds__(256) void gemm_qkv(const unsigned short* __restrict__ X,
                                                const unsigned short* __restrict__ W,
                                                unsigned short* __restrict__ QKV) {
    const int K = 1024, N = 1024;
    const int z = blockIdx.z;
    const unsigned short* A = X;
    const unsigned short* B = W + (size_t)z * (1024 * 1024);
    unsigned short* C = QKV + (size_t)z * (4096 * 1024);
    const float qs = (z == 0) ? 0.18033688011112042f : 1.0f;

    const int m0 = blockIdx.y * 128;
    const int n0 = blockIdx.x * 128;

    __shared__ unsigned short As[128 * 64];
    __shared__ unsigned short Bs[128 * 64];

    const int t = threadIdx.x;
    const int w = t >> 6;
    const int l = t & 63;
    const int wm = (w >> 1) * 64;
    const int wn = (w & 1) * 64;
    const int cl = l & 15;
    const int quad = l >> 4;

    // staging: per round, wave w covers rows w*8..w*8+7 (8 rows x 128B = 1KB)
    const int srow = l >> 3;                       // 0..7 (== LDS row & 7)
    const int scol = ((l & 7) ^ srow) * 8;         // swizzled global chunk

    f32x4 acc[4][4] = {};

    for (int k0 = 0; k0 < K; k0 += 64) {
        #pragma unroll
        for (int r = 0; r < 4; ++r)
            g2lds16(A + (size_t)(m0 + r * 32 + w * 8 + srow) * K + k0 + scol,
                    As + r * 2048 + w * 512);
        #pragma unroll
        for (int r = 0; r < 4; ++r)
            g2lds16(B + (size_t)(n0 + r * 32 + w * 8 + srow) * K + k0 + scol,
                    Bs + r * 2048 + w * 512);
        __syncthreads();                           // drains vmcnt -> LDS ready

        #pragma unroll
        for (int ks = 0; ks < 2; ++ks) {
            const int kb = (ks * 4 + quad) ^ (cl & 7);
            bf16x8 af[4], bfr[4];
            #pragma unroll
            for (int i = 0; i < 4; ++i)
                af[i] = *(const bf16x8*)(As + (wm + i * 16 + cl) * 64 + kb * 8);
            #pragma unroll
            for (int j = 0; j < 4; ++j)
                bfr[j] = *(const bf16x8*)(Bs + (wn + j * 16 + cl) * 64 + kb * 8);
            #pragma unroll
            for (int i = 0; i < 4; ++i)
                #pragma unroll
                for (int j = 0; j < 4; ++j)
                    acc[i][j] = __builtin_amdgcn_mfma_f32_16x16x32_bf16(af[i], bfr[j], acc[i][j], 0, 0, 0);
        }
        __syncthreads();
    }

    #pragma unroll
    for (int i = 0; i < 4; ++i) {
        #pragma unroll
        for (int r = 0; r < 4; ++r) {
            size_t row = (size_t)(m0 + wm + i * 16 + quad * 4 + r);
            #pragma unroll
            for (int j = 0; j < 4; ++j)
                C[row * N + (n0 + wn + j * 16 + cl)] = f2bf(acc[i][j][r] * qs);
        }
    }
}

// ---------------- V swizzle to VT3 (per bh) ---------------------------------
// VT3 element (tau, d) at (tau>>4)*1024 + (d&15)*64 + ((tau>>2)&3)*16
//                        + (d>>4)*4 + (tau&3)
__global__ __launch_bounds__(256) void vtrans(const unsigned short* __restrict__ Vn,
                                              unsigned short* __restrict__ V3) {
    const int bh = blockIdx.y;
    const int T0 = blockIdx.x * 128;
    __shared__ unsigned short L[128 * 72];
    const int t = threadIdx.x;

    const unsigned short* src = Vn + (size_t)bh * 131072 + (size_t)T0 * 64;
    #pragma unroll
    for (int p = 0; p < 4; ++p) {
        int r = p * 32 + (t >> 3), c = (t & 7) * 8;
        *(ushort8v*)(L + r * 72 + c) = *(const ushort8v*)(src + (size_t)r * 64 + c);
    }
    __syncthreads();
    unsigned short* dst = V3 + (size_t)bh * 131072 + (size_t)(T0 >> 4) * 1024;
    #pragma unroll
    for (int p = 0; p < 2; ++p) {
        int item = p * 256 + t;                 // 512 items: kb(8) x cl(16) x qk(4)
        int kb = item >> 6, cl = (item >> 2) & 15, qk = item & 3;
        ushort8v a, b;
        #pragma unroll
        for (int u = 0; u < 8; ++u) {
            int dt = u >> 2, j = u & 3;
            a[u] = L[(kb * 16 + qk * 4 + j) * 72 + dt * 16 + cl];
            b[u] = L[(kb * 16 + qk * 4 + j) * 72 + (dt + 2) * 16 + cl];
        }
        unsigned short* dp = dst + kb * 1024 + cl * 64 + qk * 16;
        *(ushort8v*)(dp) = a;
        *(ushort8v*)(dp + 8) = b;
    }
}

// ---------------- Flash attention: balanced strip-pairs, 4-way kv-split ------
// Block (256 thr) owns strips (s, 63-s): exactly 65 chunk-units -> all 1024
// blocks / 4096 waves uniform. Waves split a strip's 32-kv chunks mod 4
// (softmax associative, no running max); one LDS combine per strip.
// Register-resident P (S^T C-layout == 16x16x16 B-frag); V^T via VT3 b128.
// XCD-pinned: 4 bh per XCD.
struct KVf { bf16x8 k[4]; short8v v[4]; };

__device__ __forceinline__ void load_kv(const unsigned short* Kb, const unsigned short* Vb,
                                        int kv0, int cl, int quad, KVf& f) {
    const unsigned short* ka = Kb + (size_t)(kv0 + cl) * 64 + quad * 8;
    f.k[0] = *(const bf16x8*)(ka);                 // kt=0 dh=0
    f.k[1] = *(const bf16x8*)(ka + 32);            // kt=0 dh=1
    f.k[2] = *(const bf16x8*)(ka + 16 * 64);       // kt=1 dh=0
    f.k[3] = *(const bf16x8*)(ka + 16 * 64 + 32);  // kt=1 dh=1
    const unsigned short* va = Vb + (size_t)(kv0 >> 4) * 1024 + cl * 64 + quad * 16;
    f.v[0] = *(const short8v*)(va);                // kt=0 dt=0,1
    f.v[1] = *(const short8v*)(va + 8);            // kt=0 dt=2,3
    f.v[2] = *(const short8v*)(va + 1024);         // kt=1 dt=0,1
    f.v[3] = *(const short8v*)(va + 1024 + 8);     // kt=1 dt=2,3
}

__device__ __forceinline__ void chunk_body(const KVf& f, const bf16x8 qf[2][2],
                                           f32x4 o[2][4], float lp[2],
                                           int cl, int quad, bool masked) {
    // S^T tiles st[kt][mt]: lane holds (kv = kt*16+quad*4+r, m = mt*16+cl)
    f32x4 st[2][2] = {};
    #pragma unroll
    for (int kt = 0; kt < 2; ++kt)
        #pragma unroll
        for (int mt = 0; mt < 2; ++mt) {
            st[kt][mt] = __builtin_amdgcn_mfma_f32_16x16x32_bf16(f.k[kt * 2],     qf[mt][0], st[kt][mt], 0, 0, 0);
            st[kt][mt] = __builtin_amdgcn_mfma_f32_16x16x32_bf16(f.k[kt * 2 + 1], qf[mt][1], st[kt][mt], 0, 0, 0);
        }

    short4v pb[2][2];
    #pragma unroll
    for (int kt = 0; kt < 2; ++kt)
        #pragma unroll
        for (int mt = 0; mt < 2; ++mt) {
            float p0, p1, p2, p3;
            if (masked) {
                int lm = mt * 16 + cl, lk = kt * 16 + quad * 4;
                p0 = (lk     <= lm) ? E2(st[kt][mt][0]) : 0.f;
                p1 = (lk + 1 <= lm) ? E2(st[kt][mt][1]) : 0.f;
                p2 = (lk + 2 <= lm) ? E2(st[kt][mt][2]) : 0.f;
                p3 = (lk + 3 <= lm) ? E2(st[kt][mt][3]) : 0.f;
            } else {
                p0 = E2(st[kt][mt][0]);
                p1 = E2(st[kt][mt][1]);
                p2 = E2(st[kt][mt][2]);
                p3 = E2(st[kt][mt][3]);
            }
            lp[mt] += (p0 + p1) + (p2 + p3);
            uint2 u = { pk2bf(p0, p1), pk2bf(p2, p3) };
            short4v pv;
            __builtin_memcpy(&pv, &u, 8);
            pb[kt][mt] = pv;
        }

    // O^T tiles o[mt][dt] += V^T(dt,kt) . P^T(kt,mt)  (16x16x16, K=16)
    #pragma unroll
    for (int mt = 0; mt < 2; ++mt)
        #pragma unroll
        for (int dt = 0; dt < 4; ++dt) {
            #pragma unroll
            for (int kt = 0; kt < 2; ++kt) {
                short8v vv = f.v[kt * 2 + (dt >> 1)];
                short4v va = (dt & 1)
                    ? __builtin_shufflevector(vv, vv, 4, 5, 6, 7)
                    : __builtin_shufflevector(vv, vv, 0, 1, 2, 3);
                o[mt][dt] = __builtin_amdgcn_mfma_f32_16x16x16bf16_1k(va, pb[kt][mt], o[mt][dt], 0, 0, 0);
            }
        }
}

__global__ __launch_bounds__(256, 4) void attn(const unsigned short* __restrict__ QK,
                                               const unsigned short* __restrict__ V3,
                                               float* __restrict__ Out) {
    const int id = blockIdx.x;
    const int bh = (id & 7) * 4 + ((id >> 3) & 3);     // 4 bh per XCD
    const int pr = id >> 5;                            // strip-pair 0..31
    const int w = threadIdx.x >> 6;                    // kv-split lane 0..3
    const int l = threadIdx.x & 63;
    const int cl = l & 15;
    const int quad = l >> 4;

    const size_t bhoff = (size_t)bh * 131072;
    const unsigned short* Qb = QK + bhoff;
    const unsigned short* Kb = QK + (size_t)4194304 + bhoff;
    const unsigned short* Vb = V3 + bhoff;
    float* Ob = Out + bhoff;

    __shared__ float Ored[3][64][34];                  // partials of waves 1..3

    #pragma unroll
    for (int half = 0; half < 2; ++half) {
        const int s = half ? (63 - pr) : pr;
        const int m0 = s * 32;
        const int nch = s + 1;                         // 32-kv chunks total

        bf16x8 qf[2][2];
        #pragma unroll
        for (int mt = 0; mt < 2; ++mt) {
            const unsigned short* qa = Qb + (size_t)(m0 + mt * 16 + cl) * 64 + quad * 8;
            qf[mt][0] = *(const bf16x8*)(qa);
            qf[mt][1] = *(const bf16x8*)(qa + 32);
        }

        f32x4 o[2][4] = {};
        float lp[2] = {0.f, 0.f};

        const int nmine = (nch > w) ? ((nch - w + 3) >> 2) : 0;  // c = w, w+4, ...
        if (nmine > 0) {
            KVf fA, fB;
            load_kv(Kb, Vb, w * 32, cl, quad, fA);
            int i = 0;
            for (;;) {
                if (i + 1 < nmine) load_kv(Kb, Vb, (w + 4 * (i + 1)) * 32, cl, quad, fB);
                chunk_body(fA, qf, o, lp, cl, quad, (w + 4 * i) == nch - 1);
                if (++i >= nmine) break;
                if (i + 1 < nmine) load_kv(Kb, Vb, (w + 4 * (i + 1)) * 32, cl, quad, fA);
                chunk_body(fB, qf, o, lp, cl, quad, (w + 4 * i) == nch - 1);
                if (++i >= nmine) break;
            }
        }

        // quad-reduce lp (lanes sharing cl hold disjoint kv subsets)
        #pragma unroll
        for (int mt = 0; mt < 2; ++mt) {
            lp[mt] += __shfl_xor(lp[mt], 16);
            lp[mt] += __shfl_xor(lp[mt], 32);
        }

        // 4-way cross-wave combine (plain partial sums)
        if (w > 0) {
            float* row = &Ored[w - 1][l][0];
            #pragma unroll
            for (int mt = 0; mt < 2; ++mt)
                #pragma unroll
                for (int dt = 0; dt < 4; ++dt)
                    *(f32x4*)(row + (mt * 4 + dt) * 4) = o[mt][dt];
            row[32] = lp[0];
            row[33] = lp[1];
        }
        __syncthreads();
        if (w == 0) {
            #pragma unroll
            for (int v = 0; v < 3; ++v) {
                const float* row = &Ored[v][l][0];
                #pragma unroll
                for (int mt = 0; mt < 2; ++mt)
                    #pragma unroll
                    for (int dt = 0; dt < 4; ++dt)
                        o[mt][dt] += *(const f32x4*)(row + (mt * 4 + dt) * 4);
                lp[0] += row[32];
                lp[1] += row[33];
            }
            #pragma unroll
            for (int mt = 0; mt < 2; ++mt) {
                float inv = 1.0f / lp[mt];
                #pragma unroll
                for (int dt = 0; dt < 4; ++dt) {
                    f32x4 r = o[mt][dt];
                    r[0] *= inv; r[1] *= inv; r[2] *= inv; r[3] *= inv;
                    *(f32x4*)(Ob + (size_t)(m0 + mt * 16 + cl) * 64 + dt * 16 + quad * 4) = r;
                }
            }
        }
        __syncthreads();                               // Ored reuse across halves
    }
}

extern "C" void kernel_launch(void* const* d_in, const int* in_sizes, int n_in,
                              void* d_out, int out_size, void* d_ws, size_t ws_size,
                              hipStream_t stream) {
    const float* x  = (const float*)d_in[0];
    const float* Wq = (const float*)d_in[1];
    const float* Wk = (const float*)d_in[2];
    const float* Wv = (const float*)d_in[3];
    float* out = (float*)d_out;

    // ws: xb 8MB | wc 6MB | QKV natural 24MB | VT3 8MB = 46MB
    unsigned short* xb  = (unsigned short*)d_ws;
    unsigned short* wc  = xb + (size_t)4096 * 1024;
    unsigned short* qkv = wc + (size_t)3 * 1024 * 1024;
    unsigned short* vt  = qkv + (size_t)3 * 4096 * 1024;

    hipLaunchKernelGGL(cast_x_k, dim3(4096), dim3(256), 0, stream, x, xb);
    hipLaunchKernelGGL(cast_w_k, dim3(1024, 1, 3), dim3(256), 0, stream, Wq, Wk, Wv, wc);
    hipLaunchKernelGGL(gemm_qkv, dim3(8, 32, 3), dim3(256), 0, stream, xb, wc, qkv);
    hipLaunchKernelGGL(vtrans, dim3(16, 32), dim3(256), 0, stream, qkv + (size_t)2 * 4096 * 1024, vt);
    hipLaunchKernelGGL(attn, dim3(1024), dim3(256), 0, stream, qkv, vt, out);
}

// Round 7
// 185.340 us; speedup vs baseline: 1.4538x; 1.4538x over previous
//
#include <hip/hip_runtime.h>
#include <hip/hip_bf16.h>
#include <stdint.h>

#define AS1 __attribute__((address_space(1)))
#define AS3 __attribute__((address_space(3)))

typedef __bf16 bf16x8 __attribute__((ext_vector_type(8)));
typedef float  f32x4  __attribute__((ext_vector_type(4)));
typedef unsigned short ushort8v __attribute__((ext_vector_type(8)));
typedef unsigned short ushort4v __attribute__((ext_vector_type(4)));
typedef short short8v __attribute__((ext_vector_type(8)));
typedef short short4v __attribute__((ext_vector_type(4)));

__device__ __forceinline__ unsigned short f2bf(float f) {
    unsigned int u = __float_as_uint(f);
    u += 0x7fffu + ((u >> 16) & 1u);           // round-to-nearest-even
    return (unsigned short)(u >> 16);
}
__device__ __forceinline__ unsigned int pk2bf(float a, float b) {
    __hip_bfloat162 h = __float22bfloat162_rn(make_float2(a, b));  // x->low short
    unsigned int u;
    __builtin_memcpy(&u, &h, 4);
    return u;
}
__device__ __forceinline__ void g2lds16(const void* gp, void* lp) {
    __builtin_amdgcn_global_load_lds((AS1 void*)gp, (AS3 void*)lp, 16, 0, 0);
}
#define E2(x) __builtin_amdgcn_exp2f(x)

// ---------------- cast fp32 -> bf16 ----------------
__global__ __launch_bounds__(256) void cast_x_k(const float* __restrict__ src,
                                                unsigned short* __restrict__ dst) {
    int i = (blockIdx.x * 256 + threadIdx.x) * 4;
    float4 v = *(const float4*)(src + i);
    ushort4v o = { f2bf(v.x), f2bf(v.y), f2bf(v.z), f2bf(v.w) };
    *(ushort4v*)(dst + i) = o;
}

__global__ __launch_bounds__(256) void cast_w_k(const float* __restrict__ w0,
                                                const float* __restrict__ w1,
                                                const float* __restrict__ w2,
                                                unsigned short* __restrict__ dst) {
    int z = blockIdx.z;
    const float* s = (z == 0) ? w0 : (z == 1) ? w1 : w2;
    int i = (blockIdx.x * 256 + threadIdx.x) * 4;
    float4 v = *(const float4*)(s + i);
    ushort4v o = { f2bf(v.x), f2bf(v.y), f2bf(v.z), f2bf(v.w) };
    *(ushort4v*)(dst + (size_t)z * 1048576 + i) = o;
}

// ---------------- QKV GEMM: out = X @ W^T (NT), m97 structure (BK=32) --------
// Q (z=0) pre-scaled by 0.125*log2(e) so attn can exp2 scores directly.
__global__ __launch_bounds__(256) void gemm_qkv(const unsigned short* __restrict__ X,
                                                const unsigned short* __restrict__ W,
                                                unsigned short* __restrict__ QKV) {
    const int K = 1024, N = 1024;
    const int z = blockIdx.z;
    const unsigned short* A = X;
    const unsigned short* B = W + (size_t)z * (1024 * 1024);
    unsigned short* C = QKV + (size_t)z * (4096 * 1024);
    const float qs = (z == 0) ? 0.18033688011112042f : 1.0f;

    const int m0 = blockIdx.y * 128;
    const int n0 = blockIdx.x * 128;

    __shared__ unsigned short As[128 * 32];
    __shared__ unsigned short Bs[128 * 32];

    const int t = threadIdx.x;
    const int w = t >> 6;
    const int l = t & 63;
    const int wm = (w >> 1) * 64;
    const int wn = (w & 1) * 64;
    const int cl = l & 15;
    const int quad = l >> 4;

    const int srow = w * 16 + (l >> 2);
    const int scol = (l & 3) * 8;

    f32x4 acc[4][4] = {};

    for (int k0 = 0; k0 < K; k0 += 32) {
        g2lds16(A + (size_t)(m0 + srow) * K + k0 + scol,      As + w * 512);
        g2lds16(A + (size_t)(m0 + 64 + srow) * K + k0 + scol, As + 2048 + w * 512);
        g2lds16(B + (size_t)(n0 + srow) * K + k0 + scol,      Bs + w * 512);
        g2lds16(B + (size_t)(n0 + 64 + srow) * K + k0 + scol, Bs + 2048 + w * 512);
        __syncthreads();

        bf16x8 af[4], bfr[4];
        #pragma unroll
        for (int i = 0; i < 4; ++i)
            af[i] = *(const bf16x8*)(As + (wm + i * 16 + cl) * 32 + quad * 8);
        #pragma unroll
        for (int j = 0; j < 4; ++j)
            bfr[j] = *(const bf16x8*)(Bs + (wn + j * 16 + cl) * 32 + quad * 8);
        #pragma unroll
        for (int i = 0; i < 4; ++i)
            #pragma unroll
            for (int j = 0; j < 4; ++j)
                acc[i][j] = __builtin_amdgcn_mfma_f32_16x16x32_bf16(af[i], bfr[j], acc[i][j], 0, 0, 0);
        __syncthreads();
    }

    #pragma unroll
    for (int i = 0; i < 4; ++i) {
        #pragma unroll
        for (int r = 0; r < 4; ++r) {
            size_t row = (size_t)(m0 + wm + i * 16 + quad * 4 + r);
            #pragma unroll
            for (int j = 0; j < 4; ++j)
                C[row * N + (n0 + wn + j * 16 + cl)] = f2bf(acc[i][j][r] * qs);
        }
    }
}

// ---------------- V swizzle to VT3 (per bh) ---------------------------------
// VT3 element (tau, d) at (tau>>4)*1024 + (d&15)*64 + ((tau>>2)&3)*16
//                        + (d>>4)*4 + (tau&3)
__global__ __launch_bounds__(256) void vtrans(const unsigned short* __restrict__ Vn,
                                              unsigned short* __restrict__ V3) {
    const int bh = blockIdx.y;
    const int T0 = blockIdx.x * 128;
    __shared__ unsigned short L[128 * 72];
    const int t = threadIdx.x;

    const unsigned short* src = Vn + (size_t)bh * 131072 + (size_t)T0 * 64;
    #pragma unroll
    for (int p = 0; p < 4; ++p) {
        int r = p * 32 + (t >> 3), c = (t & 7) * 8;
        *(ushort8v*)(L + r * 72 + c) = *(const ushort8v*)(src + (size_t)r * 64 + c);
    }
    __syncthreads();
    unsigned short* dst = V3 + (size_t)bh * 131072 + (size_t)(T0 >> 4) * 1024;
    #pragma unroll
    for (int p = 0; p < 2; ++p) {
        int item = p * 256 + t;                 // 512 items: kb(8) x cl(16) x qk(4)
        int kb = item >> 6, cl = (item >> 2) & 15, qk = item & 3;
        ushort8v a, b;
        #pragma unroll
        for (int u = 0; u < 8; ++u) {
            int dt = u >> 2, j = u & 3;
            a[u] = L[(kb * 16 + qk * 4 + j) * 72 + dt * 16 + cl];
            b[u] = L[(kb * 16 + qk * 4 + j) * 72 + (dt + 2) * 16 + cl];
        }
        unsigned short* dp = dst + kb * 1024 + cl * 64 + qk * 16;
        *(ushort8v*)(dp) = a;
        *(ushort8v*)(dp + 8) = b;
    }
}

// ---------------- Flash attention: balanced strip-pairs, 4-way kv-split ------
// Block (256 thr) owns strips (s, 63-s): exactly 65 chunk-units -> all 1024
// blocks / 4096 waves uniform; all blocks resident (4/CU). Waves split a
// strip's 32-kv chunks mod 4 (softmax associative, no running max); one LDS
// combine per strip. Register-resident P (S^T C-layout == 16x16x16 B-frag);
// V^T via VT3 b128. XCD-pinned: 4 bh per XCD.
// NOTE: half-loop is `#pragma unroll 1` — unrolling it merges both halves'
// live state (2x ~114 VGPR) and causes catastrophic scratch spill (R6: 600MB).
struct KVf { bf16x8 k[4]; short8v v[4]; };

__device__ __forceinline__ void load_kv(const unsigned short* Kb, const unsigned short* Vb,
                                        int kv0, int cl, int quad, KVf& f) {
    const unsigned short* ka = Kb + (size_t)(kv0 + cl) * 64 + quad * 8;
    f.k[0] = *(const bf16x8*)(ka);                 // kt=0 dh=0
    f.k[1] = *(const bf16x8*)(ka + 32);            // kt=0 dh=1
    f.k[2] = *(const bf16x8*)(ka + 16 * 64);       // kt=1 dh=0
    f.k[3] = *(const bf16x8*)(ka + 16 * 64 + 32);  // kt=1 dh=1
    const unsigned short* va = Vb + (size_t)(kv0 >> 4) * 1024 + cl * 64 + quad * 16;
    f.v[0] = *(const short8v*)(va);                // kt=0 dt=0,1
    f.v[1] = *(const short8v*)(va + 8);            // kt=0 dt=2,3
    f.v[2] = *(const short8v*)(va + 1024);         // kt=1 dt=0,1
    f.v[3] = *(const short8v*)(va + 1024 + 8);     // kt=1 dt=2,3
}

__device__ __forceinline__ void chunk_body(const KVf& f, const bf16x8 qf[2][2],
                                           f32x4 o[2][4], float lp[2],
                                           int cl, int quad, bool masked) {
    // S^T tiles st[kt][mt]: lane holds (kv = kt*16+quad*4+r, m = mt*16+cl)
    f32x4 st[2][2] = {};
    #pragma unroll
    for (int kt = 0; kt < 2; ++kt)
        #pragma unroll
        for (int mt = 0; mt < 2; ++mt) {
            st[kt][mt] = __builtin_amdgcn_mfma_f32_16x16x32_bf16(f.k[kt * 2],     qf[mt][0], st[kt][mt], 0, 0, 0);
            st[kt][mt] = __builtin_amdgcn_mfma_f32_16x16x32_bf16(f.k[kt * 2 + 1], qf[mt][1], st[kt][mt], 0, 0, 0);
        }

    short4v pb[2][2];
    #pragma unroll
    for (int kt = 0; kt < 2; ++kt)
        #pragma unroll
        for (int mt = 0; mt < 2; ++mt) {
            float p0, p1, p2, p3;
            if (masked) {
                int lm = mt * 16 + cl, lk = kt * 16 + quad * 4;
                p0 = (lk     <= lm) ? E2(st[kt][mt][0]) : 0.f;
                p1 = (lk + 1 <= lm) ? E2(st[kt][mt][1]) : 0.f;
                p2 = (lk + 2 <= lm) ? E2(st[kt][mt][2]) : 0.f;
                p3 = (lk + 3 <= lm) ? E2(st[kt][mt][3]) : 0.f;
            } else {
                p0 = E2(st[kt][mt][0]);
                p1 = E2(st[kt][mt][1]);
                p2 = E2(st[kt][mt][2]);
                p3 = E2(st[kt][mt][3]);
            }
            lp[mt] += (p0 + p1) + (p2 + p3);
            uint2 u = { pk2bf(p0, p1), pk2bf(p2, p3) };
            short4v pv;
            __builtin_memcpy(&pv, &u, 8);
            pb[kt][mt] = pv;
        }

    // O^T tiles o[mt][dt] += V^T(dt,kt) . P^T(kt,mt)  (16x16x16, K=16)
    #pragma unroll
    for (int mt = 0; mt < 2; ++mt)
        #pragma unroll
        for (int dt = 0; dt < 4; ++dt) {
            #pragma unroll
            for (int kt = 0; kt < 2; ++kt) {
                short8v vv = f.v[kt * 2 + (dt >> 1)];
                short4v va = (dt & 1)
                    ? __builtin_shufflevector(vv, vv, 4, 5, 6, 7)
                    : __builtin_shufflevector(vv, vv, 0, 1, 2, 3);
                o[mt][dt] = __builtin_amdgcn_mfma_f32_16x16x16bf16_1k(va, pb[kt][mt], o[mt][dt], 0, 0, 0);
            }
        }
}

__global__ __launch_bounds__(256) void attn(const unsigned short* __restrict__ QK,
                                            const unsigned short* __restrict__ V3,
                                            float* __restrict__ Out) {
    const int id = blockIdx.x;
    const int bh = (id & 7) * 4 + ((id >> 3) & 3);     // 4 bh per XCD
    const int pr = id >> 5;                            // strip-pair 0..31
    const int w = threadIdx.x >> 6;                    // kv-split lane 0..3
    const int l = threadIdx.x & 63;
    const int cl = l & 15;
    const int quad = l >> 4;

    const size_t bhoff = (size_t)bh * 131072;
    const unsigned short* Qb = QK + bhoff;
    const unsigned short* Kb = QK + (size_t)4194304 + bhoff;
    const unsigned short* Vb = V3 + bhoff;
    float* Ob = Out + bhoff;

    __shared__ float Ored[3][64][34];                  // partials of waves 1..3

    #pragma unroll 1
    for (int half = 0; half < 2; ++half) {
        const int s = half ? (63 - pr) : pr;
        const int m0 = s * 32;
        const int nch = s + 1;                         // 32-kv chunks total

        bf16x8 qf[2][2];
        #pragma unroll
        for (int mt = 0; mt < 2; ++mt) {
            const unsigned short* qa = Qb + (size_t)(m0 + mt * 16 + cl) * 64 + quad * 8;
            qf[mt][0] = *(const bf16x8*)(qa);
            qf[mt][1] = *(const bf16x8*)(qa + 32);
        }

        f32x4 o[2][4] = {};
        float lp[2] = {0.f, 0.f};

        const int nmine = (nch > w) ? ((nch - w + 3) >> 2) : 0;  // c = w, w+4, ...
        if (nmine > 0) {
            KVf fA, fB;
            load_kv(Kb, Vb, w * 32, cl, quad, fA);
            int i = 0;
            for (;;) {
                if (i + 1 < nmine) load_kv(Kb, Vb, (w + 4 * (i + 1)) * 32, cl, quad, fB);
                chunk_body(fA, qf, o, lp, cl, quad, (w + 4 * i) == nch - 1);
                if (++i >= nmine) break;
                if (i + 1 < nmine) load_kv(Kb, Vb, (w + 4 * (i + 1)) * 32, cl, quad, fA);
                chunk_body(fB, qf, o, lp, cl, quad, (w + 4 * i) == nch - 1);
                if (++i >= nmine) break;
            }
        }

        // quad-reduce lp (lanes sharing cl hold disjoint kv subsets)
        #pragma unroll
        for (int mt = 0; mt < 2; ++mt) {
            lp[mt] += __shfl_xor(lp[mt], 16);
            lp[mt] += __shfl_xor(lp[mt], 32);
        }

        // 4-way cross-wave combine (plain partial sums)
        if (w > 0) {
            float* row = &Ored[w - 1][l][0];
            #pragma unroll
            for (int mt = 0; mt < 2; ++mt)
                #pragma unroll
                for (int dt = 0; dt < 4; ++dt)
                    *(f32x4*)(row + (mt * 4 + dt) * 4) = o[mt][dt];
            row[32] = lp[0];
            row[33] = lp[1];
        }
        __syncthreads();
        if (w == 0) {
            #pragma unroll
            for (int v = 0; v < 3; ++v) {
                const float* row = &Ored[v][l][0];
                #pragma unroll
                for (int mt = 0; mt < 2; ++mt)
                    #pragma unroll
                    for (int dt = 0; dt < 4; ++dt)
                        o[mt][dt] += *(const f32x4*)(row + (mt * 4 + dt) * 4);
                lp[0] += row[32];
                lp[1] += row[33];
            }
            #pragma unroll
            for (int mt = 0; mt < 2; ++mt) {
                float inv = 1.0f / lp[mt];
                #pragma unroll
                for (int dt = 0; dt < 4; ++dt) {
                    f32x4 r = o[mt][dt];
                    r[0] *= inv; r[1] *= inv; r[2] *= inv; r[3] *= inv;
                    *(f32x4*)(Ob + (size_t)(m0 + mt * 16 + cl) * 64 + dt * 16 + quad * 4) = r;
                }
            }
        }
        __syncthreads();                               // Ored reuse across halves
    }
}

extern "C" void kernel_launch(void* const* d_in, const int* in_sizes, int n_in,
                              void* d_out, int out_size, void* d_ws, size_t ws_size,
                              hipStream_t stream) {
    const float* x  = (const float*)d_in[0];
    const float* Wq = (const float*)d_in[1];
    const float* Wk = (const float*)d_in[2];
    const float* Wv = (const float*)d_in[3];
    float* out = (float*)d_out;

    // ws: xb 8MB | wc 6MB | QKV natural 24MB | VT3 8MB = 46MB
    unsigned short* xb  = (unsigned short*)d_ws;
    unsigned short* wc  = xb + (size_t)4096 * 1024;
    unsigned short* qkv = wc + (size_t)3 * 1024 * 1024;
    unsigned short* vt  = qkv + (size_t)3 * 4096 * 1024;

    hipLaunchKernelGGL(cast_x_k, dim3(4096), dim3(256), 0, stream, x, xb);
    hipLaunchKernelGGL(cast_w_k, dim3(1024, 1, 3), dim3(256), 0, stream, Wq, Wk, Wv, wc);
    hipLaunchKernelGGL(gemm_qkv, dim3(8, 32, 3), dim3(256), 0, stream, xb, wc, qkv);
    hipLaunchKernelGGL(vtrans, dim3(16, 32), dim3(256), 0, stream, qkv + (size_t)2 * 4096 * 1024, vt);
    hipLaunchKernelGGL(attn, dim3(1024), dim3(256), 0, stream, qkv, vt, out);
}